// Round 1
// baseline (1055.587 us; speedup 1.0000x reference)
//
#include <hip/hip_runtime.h>

#define B_ 4
#define N_ 1000000
#define K_ 2048
#define P_ 1000
#define CAP_ 8192
#define NSLOT_ 4
#define THR_ 0.7f

// ---- workspace layout (bytes) ----
// hist   : B * 65536 * NSLOT * 4 = 4,194,304
// meta   : 256  (per batch: [0]=threshold bucket, [1]=candidate count)
// cand   : B * CAP * 8          = 262,144   (uint2: key, idx)
// topidx : B * K * 4            = 32,768
// boxes  : B * K * 16           = 131,072
// mask   : B * K * 32 * 8       = 2,097,152
#define OFF_HIST 0
#define OFF_META 4194304
#define OFF_CAND (OFF_META + 256)
#define OFF_TOPI (OFF_CAND + 262144)
#define OFF_BOX  (OFF_TOPI + 32768)
#define OFF_MASK (OFF_BOX + 131072)

__device__ __forceinline__ unsigned fkey(float f) {
  unsigned u = __float_as_uint(f);
  return (u & 0x80000000u) ? ~u : (u | 0x80000000u);
}

__device__ __forceinline__ unsigned long long readlane64(unsigned long long v, int l) {
  unsigned lo = (unsigned)__builtin_amdgcn_readlane((int)(unsigned)(v & 0xffffffffull), l);
  unsigned hi = (unsigned)__builtin_amdgcn_readlane((int)(unsigned)(v >> 32), l);
  return ((unsigned long long)hi << 32) | (unsigned long long)lo;
}

// ---- K1: histogram of top-16 bits of monotonic key ----
__global__ void hist_kernel(const float2* __restrict__ probs, unsigned* __restrict__ hist) {
  int b = blockIdx.y;
  int i = blockIdx.x * 256 + threadIdx.x;
  if (i >= N_) return;
  float s = probs[(size_t)b * N_ + i].y;
  unsigned key = fkey(s);
  unsigned bucket = key >> 16;
  atomicAdd(&hist[(((unsigned)b << 16) | bucket) * NSLOT_ + (blockIdx.x & (NSLOT_ - 1))], 1u);
}

// ---- K2: find smallest bucket cb with count(bucket >= cb) >= K ----
__global__ void select_kernel(const unsigned* __restrict__ hist, unsigned* __restrict__ meta) {
  int b = blockIdx.x, t = threadIdx.x;  // 256 threads
  __shared__ unsigned suf[256];
  __shared__ int tc_s;
  __shared__ unsigned above_s;
  const uint4* h4 = (const uint4*)(hist + (((size_t)b) << 16) * NSLOT_);
  unsigned sum = 0;
  for (int j = 0; j < 256; ++j) {
    uint4 v = h4[t * 256 + j];
    sum += v.x + v.y + v.z + v.w;
  }
  suf[t] = sum;
  __syncthreads();
  for (int off = 1; off < 256; off <<= 1) {
    unsigned add = (t + off < 256) ? suf[t + off] : 0u;
    __syncthreads();
    suf[t] += add;
    __syncthreads();
  }
  unsigned nxt = (t < 255) ? suf[t + 1] : 0u;
  if (suf[t] >= K_ && (t == 255 || nxt < K_)) { tc_s = t; above_s = nxt; }
  __syncthreads();
  int tc = tc_s;
  unsigned above = above_s;
  unsigned bs;
  { uint4 v = h4[tc * 256 + t]; bs = v.x + v.y + v.z + v.w; }
  __syncthreads();
  suf[t] = bs;
  __syncthreads();
  for (int off = 1; off < 256; off <<= 1) {
    unsigned add = (t + off < 256) ? suf[t + off] : 0u;
    __syncthreads();
    suf[t] += add;
    __syncthreads();
  }
  unsigned nxt2 = (t < 255) ? suf[t + 1] : 0u;
  if (above + suf[t] >= K_ && (t == 255 || above + nxt2 < K_))
    meta[b * 4 + 0] = (unsigned)(tc * 256 + t);
}

// ---- K3: compact candidates (bucket >= cb) with wave-aggregated atomics ----
__global__ void compact_kernel(const float2* __restrict__ probs, unsigned* __restrict__ meta,
                               uint2* __restrict__ cand) {
  int b = blockIdx.y;
  int i = blockIdx.x * 256 + threadIdx.x;
  unsigned cb = meta[b * 4 + 0];
  bool pass = false;
  unsigned key = 0;
  if (i < N_) {
    float s = probs[(size_t)b * N_ + i].y;
    key = fkey(s);
    pass = (key >> 16) >= cb;
  }
  unsigned long long m = __ballot(pass);
  if (pass) {
    int lane = threadIdx.x & 63;
    int leader = __ffsll((unsigned long long)m) - 1;
    unsigned base = 0;
    if (lane == leader) base = atomicAdd(&meta[b * 4 + 1], (unsigned)__popcll(m));
    base = __shfl(base, leader, 64);
    unsigned pos = base + (unsigned)__popcll(m & ((1ull << lane) - 1ull));
    if (pos < CAP_) cand[(size_t)b * CAP_ + pos] = make_uint2(key, (unsigned)i);
  }
}

// ---- K4: exact rank by counting (stable: key desc, idx asc) ----
__global__ void rank_kernel(const uint2* __restrict__ cand, const unsigned* __restrict__ meta,
                            unsigned* __restrict__ topidx) {
  int b = blockIdx.y;
  unsigned M = meta[b * 4 + 1];
  if (M > CAP_) M = CAP_;
  if ((unsigned)(blockIdx.x * 256) >= M) return;  // uniform per block, before barriers
  __shared__ uint2 tile[1024];
  int ci = blockIdx.x * 256 + threadIdx.x;
  bool act = ci < (int)M;
  uint2 me = make_uint2(0u, 0u);
  if (act) me = cand[(size_t)b * CAP_ + ci];
  unsigned long long my = ((unsigned long long)me.x << 32) | (unsigned long long)(unsigned)(~me.y);
  unsigned rank = 0;
  for (unsigned base = 0; base < M; base += 1024) {
    unsigned n = (M - base < 1024u) ? (M - base) : 1024u;
    for (unsigned t = threadIdx.x; t < n; t += 256) tile[t] = cand[(size_t)b * CAP_ + base + t];
    __syncthreads();
    if (act) {
      unsigned n2 = n >> 1;
      const uint4* t4 = (const uint4*)tile;
      for (unsigned j = 0; j < n2; ++j) {
        uint4 v = t4[j];
        unsigned long long c0 = ((unsigned long long)v.x << 32) | (unsigned long long)(unsigned)(~v.y);
        unsigned long long c1 = ((unsigned long long)v.z << 32) | (unsigned long long)(unsigned)(~v.w);
        rank += (unsigned)(c0 > my) + (unsigned)(c1 > my);
      }
      if (n & 1) {
        uint2 v = tile[n - 1];
        unsigned long long c0 = ((unsigned long long)v.x << 32) | (unsigned long long)(unsigned)(~v.y);
        rank += (unsigned)(c0 > my);
      }
    }
    __syncthreads();
  }
  if (act && rank < K_) topidx[(b << 11) + rank] = me.y;
}

// ---- K5: gather anchors/deltas, decode boxes, clip ----
__global__ void boxes_kernel(const unsigned* __restrict__ topidx, const float4* __restrict__ bbox,
                             const float4* __restrict__ anch, float4* __restrict__ boxes) {
  int g = blockIdx.x * 256 + threadIdx.x;  // B_*K_
  int b = g >> 11;
  unsigned idx = topidx[g];
  size_t base = (size_t)b * N_ + idx;
  float4 a = anch[base];
  float4 d = bbox[base];
  float d0 = d.x * 0.1f, d1 = d.y * 0.1f, d2 = d.z * 0.2f, d3 = d.w * 0.2f;
  float h = a.z - a.x, w = a.w - a.y;
  float cy = (a.x + 0.5f * h) + d0 * h;
  float cx = (a.y + 0.5f * w) + d1 * w;
  float h2 = h * expf(d2);
  float w2 = w * expf(d3);
  float y1 = cy - 0.5f * h2, x1 = cx - 0.5f * w2;
  float y2 = cy + 0.5f * h2, x2 = cx + 0.5f * w2;
  y1 = fminf(fmaxf(y1, 0.f), 1.f);
  x1 = fminf(fmaxf(x1, 0.f), 1.f);
  y2 = fminf(fmaxf(y2, 0.f), 1.f);
  x2 = fminf(fmaxf(x2, 0.f), 1.f);
  boxes[g] = make_float4(y1, x1, y2, x2);
}

// ---- K6: IoU suppression bitmask, one 64-bit word per wave-ballot ----
__global__ void mask_kernel(const float4* __restrict__ boxes, unsigned long long* __restrict__ mask) {
  int wid = blockIdx.x * 4 + (threadIdx.x >> 6);  // 16384 waves total
  int lane = threadIdx.x & 63;
  int b = wid >> 12;         // 4096 waves per batch
  int rb = (wid >> 5) & 127; // row block of 16
  int jb = wid & 31;         // 64-column block
  int j = (jb << 6) + lane;
  float4 bj = boxes[(b << 11) + j];
  float areaJ = (bj.z - bj.x) * (bj.w - bj.y);
#pragma unroll
  for (int r = 0; r < 16; ++r) {
    int i = (rb << 4) + r;
    float4 bi = boxes[(b << 11) + i];
    float areaI = (bi.z - bi.x) * (bi.w - bi.y);
    float yA = fmaxf(bi.x, bj.x), xA = fmaxf(bi.y, bj.y);
    float yB = fminf(bi.z, bj.z), xB = fminf(bi.w, bj.w);
    float ih = fmaxf(yB - yA, 0.f), iw = fmaxf(xB - xA, 0.f);
    float inter = ih * iw;
    float uni = areaI + areaJ - inter;
    float iou = inter / (uni + 1e-8f);
    bool pred = (iou > THR_) && (j > i);
    unsigned long long bits = __ballot(pred);
    if (lane == 0) mask[((size_t)((b << 11) + i) << 5) + jb] = bits;
  }
}

// ---- K7: sequential greedy NMS reduce + output ----
__global__ void nms_kernel(const unsigned long long* __restrict__ mask,
                           const float4* __restrict__ boxes, float4* __restrict__ out) {
  int b = blockIdx.x;
  int lane = threadIdx.x;  // 64 threads = 1 wave
  __shared__ unsigned long long keptm[32];
  __shared__ int pre[32];
  __shared__ int sel[P_];
  if (lane < 32) keptm[lane] = 0ull;
  for (int r = lane; r < P_; r += 64) sel[r] = -1;
  __syncthreads();
  unsigned long long rem = 0ull;  // lane w (<32) owns suppressed-bits word w
  int cnt = 0;
  for (int c = 0; c < 32; ++c) {
    // lane k holds row (c*64+k)'s word c (intra-chunk suppression)
    unsigned long long rin = mask[((size_t)((b << 11) + (c << 6) + lane) << 5) + c];
    unsigned long long cur = readlane64(rem, c);
    unsigned long long kept = 0ull;
#pragma unroll
    for (int k = 0; k < 64; ++k) {
      unsigned long long rk = readlane64(rin, k);
      unsigned long long alive = ((cur >> k) & 1ull) ^ 1ull;
      unsigned long long selm = 0ull - alive;
      cur |= rk & selm;
      kept |= alive << k;
    }
    if (lane == 0) keptm[c] = kept;
    cnt += (int)__popcll(kept);
    // fold kept rows' full masks into rem (lane-parallel over words)
    if (lane < 32) {
      const unsigned long long* rowp = mask + (((size_t)((b << 11) + (c << 6))) << 5) + lane;
#pragma unroll 8
      for (int k = 0; k < 64; ++k) {
        unsigned long long row = rowp[(size_t)k << 5];
        unsigned long long s = 0ull - ((kept >> k) & 1ull);
        rem |= row & s;
      }
    }
    if (cnt >= P_) break;  // later chunks cannot affect the first 1000 kept
  }
  __syncthreads();
  if (lane == 0) {
    int run = 0;
    for (int c = 0; c < 32; ++c) { pre[c] = run; run += (int)__popcll(keptm[c]); }
  }
  __syncthreads();
  for (int i = lane; i < K_; i += 64) {
    int c = i >> 6, k = i & 63;
    unsigned long long km = keptm[c];
    if ((km >> k) & 1ull) {
      int rank = pre[c] + (int)__popcll(km & ((1ull << k) - 1ull));
      if (rank < P_) sel[rank] = i;
    }
  }
  __syncthreads();
  for (int r = lane; r < P_; r += 64) {
    int i = sel[r];
    float4 v = make_float4(0.f, 0.f, 0.f, 0.f);
    if (i >= 0) v = boxes[(b << 11) + i];
    out[b * P_ + r] = v;
  }
}

extern "C" void kernel_launch(void* const* d_in, const int* in_sizes, int n_in,
                              void* d_out, int out_size, void* d_ws, size_t ws_size,
                              hipStream_t stream) {
  const float2* probs = (const float2*)d_in[0];      // (B,N,2) -> float2 per elem
  const float4* bbox  = (const float4*)d_in[1];      // (B,N,4)
  const float4* anch  = (const float4*)d_in[2];      // (B,N,4)
  char* ws = (char*)d_ws;
  unsigned* hist = (unsigned*)(ws + OFF_HIST);
  unsigned* meta = (unsigned*)(ws + OFF_META);
  uint2* cand = (uint2*)(ws + OFF_CAND);
  unsigned* topidx = (unsigned*)(ws + OFF_TOPI);
  float4* boxes = (float4*)(ws + OFF_BOX);
  unsigned long long* mask = (unsigned long long*)(ws + OFF_MASK);
  float4* out = (float4*)d_out;

  hipMemsetAsync(ws, 0, OFF_CAND, stream);  // zero hist + meta (ws is poisoned 0xAA)

  dim3 gScan((N_ + 255) / 256, B_);
  hist_kernel<<<gScan, 256, 0, stream>>>(probs, hist);
  select_kernel<<<B_, 256, 0, stream>>>(hist, meta);
  compact_kernel<<<gScan, 256, 0, stream>>>(probs, meta, cand);
  rank_kernel<<<dim3(CAP_ / 256, B_), 256, 0, stream>>>(cand, meta, topidx);
  boxes_kernel<<<(B_ * K_) / 256, 256, 0, stream>>>(topidx, bbox, anch, boxes);
  mask_kernel<<<(B_ * 128 * 32) / 4, 256, 0, stream>>>(boxes, mask);
  nms_kernel<<<B_, 64, 0, stream>>>(mask, boxes, out);
}

// Round 2
// 506.355 us; speedup vs baseline: 2.0847x; 2.0847x over previous
//
#include <hip/hip_runtime.h>

#define B_ 4
#define N_ 1000000
#define K_ 2048
#define P_ 1000
#define CAP_ 8192
#define THR_ 0.7f

// ---- workspace layout (bytes) ----
// hist   : B * 65536 * 4 = 1,048,576
// meta   : 256  (per batch: [0]=threshold bucket, [1]=candidate count)
// cand   : B * CAP * 8   = 262,144   (uint2: key, idx)
// topidx : B * K * 4     = 32,768
// boxes  : B * K * 16    = 131,072
// mask   : B * K * 32 * 8 = 2,097,152
#define OFF_HIST 0
#define OFF_META 1048576
#define OFF_CAND (OFF_META + 256)
#define OFF_TOPI (OFF_CAND + 262144)
#define OFF_BOX  (OFF_TOPI + 32768)
#define OFF_MASK (OFF_BOX + 131072)

__device__ __forceinline__ unsigned fkey(float f) {
  unsigned u = __float_as_uint(f);
  return (u & 0x80000000u) ? ~u : (u | 0x80000000u);
}

__device__ __forceinline__ unsigned long long readlane64(unsigned long long v, int l) {
  unsigned lo = (unsigned)__builtin_amdgcn_readlane((int)(unsigned)(v & 0xffffffffull), l);
  unsigned hi = (unsigned)__builtin_amdgcn_readlane((int)(unsigned)(v >> 32), l);
  return ((unsigned long long)hi << 32) | (unsigned long long)lo;
}

// ---- K1: LDS-privatized histogram of top-16 bits of monotonic key ----
// 65536 buckets as packed u16 pairs: 32768 LDS words = 128 KB (1 block/CU).
// Per-block elements <= 16*1024 = 16384 < 65536, so no packed-half overflow.
__global__ void __launch_bounds__(256) hist_kernel(const float* __restrict__ probs,
                                                   unsigned* __restrict__ hist) {
  int b = blockIdx.y;
  __shared__ unsigned h[32768];
  for (int i = threadIdx.x; i < 32768; i += 256) h[i] = 0u;
  __syncthreads();
  const float4* p4 = (const float4*)(probs + (size_t)b * (2 * (size_t)N_));
  const int ntiles = (N_ + 1023) / 1024;  // 977
  for (int tile = blockIdx.x; tile < ntiles; tile += gridDim.x) {
    int e0 = tile * 1024 + threadIdx.x * 4;  // 4 elements per thread per tile
    if (e0 + 3 < N_) {
      float4 a = p4[e0 >> 1];        // elements e0, e0+1 (scores in .y, .w)
      float4 c = p4[(e0 >> 1) + 1];  // elements e0+2, e0+3
      unsigned b0 = fkey(a.y) >> 16, b1 = fkey(a.w) >> 16;
      unsigned b2 = fkey(c.y) >> 16, b3 = fkey(c.w) >> 16;
      atomicAdd(&h[b0 >> 1], 1u << ((b0 & 1u) << 4));
      atomicAdd(&h[b1 >> 1], 1u << ((b1 & 1u) << 4));
      atomicAdd(&h[b2 >> 1], 1u << ((b2 & 1u) << 4));
      atomicAdd(&h[b3 >> 1], 1u << ((b3 & 1u) << 4));
    } else {
      for (int e = e0; e < N_ && e < e0 + 4; ++e) {
        float s = probs[(size_t)b * 2 * N_ + 2 * (size_t)e + 1];
        unsigned bk = fkey(s) >> 16;
        atomicAdd(&h[bk >> 1], 1u << ((bk & 1u) << 4));
      }
    }
  }
  __syncthreads();
  // flush nonzero counters to the per-batch global histogram
  unsigned* g = hist + ((size_t)b << 16);
  for (int w = threadIdx.x; w < 32768; w += 256) {
    unsigned v = h[w];
    if (v) {
      unsigned c0 = v & 0xFFFFu, c1 = v >> 16;
      if (c0) atomicAdd(&g[2 * w], c0);
      if (c1) atomicAdd(&g[2 * w + 1], c1);
    }
  }
}

// ---- K2: find smallest bucket cb with count(bucket >= cb) >= K ----
__global__ void select_kernel(const unsigned* __restrict__ hist, unsigned* __restrict__ meta) {
  int b = blockIdx.x, t = threadIdx.x;  // 256 threads
  __shared__ unsigned suf[256];
  __shared__ int tc_s;
  __shared__ unsigned above_s;
  const unsigned* g = hist + ((size_t)b << 16);
  const uint4* h4 = (const uint4*)g;
  // coarse: thread t sums buckets [t*256, (t+1)*256)
  unsigned sum = 0;
  for (int j = 0; j < 64; ++j) {
    uint4 v = h4[t * 64 + j];
    sum += v.x + v.y + v.z + v.w;
  }
  suf[t] = sum;
  __syncthreads();
  for (int off = 1; off < 256; off <<= 1) {
    unsigned add = (t + off < 256) ? suf[t + off] : 0u;
    __syncthreads();
    suf[t] += add;
    __syncthreads();
  }
  unsigned nxt = (t < 255) ? suf[t + 1] : 0u;
  if (suf[t] >= K_ && (t == 255 || nxt < K_)) { tc_s = t; above_s = nxt; }
  __syncthreads();
  int tc = tc_s;
  unsigned above = above_s;
  // fine: thread t handles bucket tc*256 + t
  unsigned bs = g[tc * 256 + t];
  __syncthreads();
  suf[t] = bs;
  __syncthreads();
  for (int off = 1; off < 256; off <<= 1) {
    unsigned add = (t + off < 256) ? suf[t + off] : 0u;
    __syncthreads();
    suf[t] += add;
    __syncthreads();
  }
  unsigned nxt2 = (t < 255) ? suf[t + 1] : 0u;
  if (above + suf[t] >= K_ && (t == 255 || above + nxt2 < K_))
    meta[b * 4 + 0] = (unsigned)(tc * 256 + t);
}

// ---- K3: compact candidates (bucket >= cb) with wave-aggregated atomics ----
__global__ void compact_kernel(const float2* __restrict__ probs, unsigned* __restrict__ meta,
                               uint2* __restrict__ cand) {
  int b = blockIdx.y;
  int i = blockIdx.x * 256 + threadIdx.x;
  unsigned cb = meta[b * 4 + 0];
  bool pass = false;
  unsigned key = 0;
  if (i < N_) {
    float s = probs[(size_t)b * N_ + i].y;
    key = fkey(s);
    pass = (key >> 16) >= cb;
  }
  unsigned long long m = __ballot(pass);
  if (pass) {
    int lane = threadIdx.x & 63;
    int leader = __ffsll((unsigned long long)m) - 1;
    unsigned base = 0;
    if (lane == leader) base = atomicAdd(&meta[b * 4 + 1], (unsigned)__popcll(m));
    base = __shfl(base, leader, 64);
    unsigned pos = base + (unsigned)__popcll(m & ((1ull << lane) - 1ull));
    if (pos < CAP_) cand[(size_t)b * CAP_ + pos] = make_uint2(key, (unsigned)i);
  }
}

// ---- K4: exact rank by counting (stable: key desc, idx asc) ----
__global__ void rank_kernel(const uint2* __restrict__ cand, const unsigned* __restrict__ meta,
                            unsigned* __restrict__ topidx) {
  int b = blockIdx.y;
  unsigned M = meta[b * 4 + 1];
  if (M > CAP_) M = CAP_;
  if ((unsigned)(blockIdx.x * 256) >= M) return;  // uniform per block, before barriers
  __shared__ uint2 tile[1024];
  int ci = blockIdx.x * 256 + threadIdx.x;
  bool act = ci < (int)M;
  uint2 me = make_uint2(0u, 0u);
  if (act) me = cand[(size_t)b * CAP_ + ci];
  unsigned long long my = ((unsigned long long)me.x << 32) | (unsigned long long)(unsigned)(~me.y);
  unsigned rank = 0;
  for (unsigned base = 0; base < M; base += 1024) {
    unsigned n = (M - base < 1024u) ? (M - base) : 1024u;
    for (unsigned t = threadIdx.x; t < n; t += 256) tile[t] = cand[(size_t)b * CAP_ + base + t];
    __syncthreads();
    if (act) {
      unsigned n2 = n >> 1;
      const uint4* t4 = (const uint4*)tile;
      for (unsigned j = 0; j < n2; ++j) {
        uint4 v = t4[j];
        unsigned long long c0 = ((unsigned long long)v.x << 32) | (unsigned long long)(unsigned)(~v.y);
        unsigned long long c1 = ((unsigned long long)v.z << 32) | (unsigned long long)(unsigned)(~v.w);
        rank += (unsigned)(c0 > my) + (unsigned)(c1 > my);
      }
      if (n & 1) {
        uint2 v = tile[n - 1];
        unsigned long long c0 = ((unsigned long long)v.x << 32) | (unsigned long long)(unsigned)(~v.y);
        rank += (unsigned)(c0 > my);
      }
    }
    __syncthreads();
  }
  if (act && rank < K_) topidx[(b << 11) + rank] = me.y;
}

// ---- K5: gather anchors/deltas, decode boxes, clip ----
__global__ void boxes_kernel(const unsigned* __restrict__ topidx, const float4* __restrict__ bbox,
                             const float4* __restrict__ anch, float4* __restrict__ boxes) {
  int g = blockIdx.x * 256 + threadIdx.x;  // B_*K_
  int b = g >> 11;
  unsigned idx = topidx[g];
  size_t base = (size_t)b * N_ + idx;
  float4 a = anch[base];
  float4 d = bbox[base];
  float d0 = d.x * 0.1f, d1 = d.y * 0.1f, d2 = d.z * 0.2f, d3 = d.w * 0.2f;
  float h = a.z - a.x, w = a.w - a.y;
  float cy = (a.x + 0.5f * h) + d0 * h;
  float cx = (a.y + 0.5f * w) + d1 * w;
  float h2 = h * expf(d2);
  float w2 = w * expf(d3);
  float y1 = cy - 0.5f * h2, x1 = cx - 0.5f * w2;
  float y2 = cy + 0.5f * h2, x2 = cx + 0.5f * w2;
  y1 = fminf(fmaxf(y1, 0.f), 1.f);
  x1 = fminf(fmaxf(x1, 0.f), 1.f);
  y2 = fminf(fmaxf(y2, 0.f), 1.f);
  x2 = fminf(fmaxf(x2, 0.f), 1.f);
  boxes[g] = make_float4(y1, x1, y2, x2);
}

// ---- K6: IoU suppression bitmask, one 64-bit word per wave-ballot ----
__global__ void mask_kernel(const float4* __restrict__ boxes, unsigned long long* __restrict__ mask) {
  int wid = blockIdx.x * 4 + (threadIdx.x >> 6);  // 16384 waves total
  int lane = threadIdx.x & 63;
  int b = wid >> 12;         // 4096 waves per batch
  int rb = (wid >> 5) & 127; // row block of 16
  int jb = wid & 31;         // 64-column block
  int j = (jb << 6) + lane;
  float4 bj = boxes[(b << 11) + j];
  float areaJ = (bj.z - bj.x) * (bj.w - bj.y);
#pragma unroll
  for (int r = 0; r < 16; ++r) {
    int i = (rb << 4) + r;
    float4 bi = boxes[(b << 11) + i];
    float areaI = (bi.z - bi.x) * (bi.w - bi.y);
    float yA = fmaxf(bi.x, bj.x), xA = fmaxf(bi.y, bj.y);
    float yB = fminf(bi.z, bj.z), xB = fminf(bi.w, bj.w);
    float ih = fmaxf(yB - yA, 0.f), iw = fmaxf(xB - xA, 0.f);
    float inter = ih * iw;
    float uni = areaI + areaJ - inter;
    float iou = inter / (uni + 1e-8f);
    bool pred = (iou > THR_) && (j > i);
    unsigned long long bits = __ballot(pred);
    if (lane == 0) mask[((size_t)((b << 11) + i) << 5) + jb] = bits;
  }
}

// ---- K7: sequential greedy NMS reduce + output ----
__global__ void nms_kernel(const unsigned long long* __restrict__ mask,
                           const float4* __restrict__ boxes, float4* __restrict__ out) {
  int b = blockIdx.x;
  int lane = threadIdx.x;  // 64 threads = 1 wave
  __shared__ unsigned long long keptm[32];
  __shared__ int pre[32];
  __shared__ int sel[P_];
  if (lane < 32) keptm[lane] = 0ull;
  for (int r = lane; r < P_; r += 64) sel[r] = -1;
  __syncthreads();
  unsigned long long rem = 0ull;  // lane w (<32) owns suppressed-bits word w
  int cnt = 0;
  for (int c = 0; c < 32; ++c) {
    // lane k holds row (c*64+k)'s word c (intra-chunk suppression)
    unsigned long long rin = mask[((size_t)((b << 11) + (c << 6) + lane) << 5) + c];
    unsigned long long cur = readlane64(rem, c);
    unsigned long long kept = 0ull;
#pragma unroll
    for (int k = 0; k < 64; ++k) {
      unsigned long long rk = readlane64(rin, k);
      unsigned long long alive = ((cur >> k) & 1ull) ^ 1ull;
      unsigned long long selm = 0ull - alive;
      cur |= rk & selm;
      kept |= alive << k;
    }
    if (lane == 0) keptm[c] = kept;
    cnt += (int)__popcll(kept);
    // fold kept rows' full masks into rem (lane-parallel over words)
    if (lane < 32) {
      const unsigned long long* rowp = mask + (((size_t)((b << 11) + (c << 6))) << 5) + lane;
#pragma unroll 8
      for (int k = 0; k < 64; ++k) {
        unsigned long long row = rowp[(size_t)k << 5];
        unsigned long long s = 0ull - ((kept >> k) & 1ull);
        rem |= row & s;
      }
    }
    if (cnt >= P_) break;  // later chunks cannot affect the first 1000 kept
  }
  __syncthreads();
  if (lane == 0) {
    int run = 0;
    for (int c = 0; c < 32; ++c) { pre[c] = run; run += (int)__popcll(keptm[c]); }
  }
  __syncthreads();
  for (int i = lane; i < K_; i += 64) {
    int c = i >> 6, k = i & 63;
    unsigned long long km = keptm[c];
    if ((km >> k) & 1ull) {
      int rank = pre[c] + (int)__popcll(km & ((1ull << k) - 1ull));
      if (rank < P_) sel[rank] = i;
    }
  }
  __syncthreads();
  for (int r = lane; r < P_; r += 64) {
    int i = sel[r];
    float4 v = make_float4(0.f, 0.f, 0.f, 0.f);
    if (i >= 0) v = boxes[(b << 11) + i];
    out[b * P_ + r] = v;
  }
}

extern "C" void kernel_launch(void* const* d_in, const int* in_sizes, int n_in,
                              void* d_out, int out_size, void* d_ws, size_t ws_size,
                              hipStream_t stream) {
  const float* probs_f = (const float*)d_in[0];      // (B,N,2)
  const float2* probs2 = (const float2*)d_in[0];
  const float4* bbox   = (const float4*)d_in[1];     // (B,N,4)
  const float4* anch   = (const float4*)d_in[2];     // (B,N,4)
  char* ws = (char*)d_ws;
  unsigned* hist = (unsigned*)(ws + OFF_HIST);
  unsigned* meta = (unsigned*)(ws + OFF_META);
  uint2* cand = (uint2*)(ws + OFF_CAND);
  unsigned* topidx = (unsigned*)(ws + OFF_TOPI);
  float4* boxes = (float4*)(ws + OFF_BOX);
  unsigned long long* mask = (unsigned long long*)(ws + OFF_MASK);
  float4* out = (float4*)d_out;

  hipMemsetAsync(ws, 0, OFF_CAND, stream);  // zero hist + meta (ws is poisoned 0xAA)

  hist_kernel<<<dim3(64, B_), 256, 0, stream>>>(probs_f, hist);
  select_kernel<<<B_, 256, 0, stream>>>(hist, meta);
  compact_kernel<<<dim3((N_ + 255) / 256, B_), 256, 0, stream>>>(probs2, meta, cand);
  rank_kernel<<<dim3(CAP_ / 256, B_), 256, 0, stream>>>(cand, meta, topidx);
  boxes_kernel<<<(B_ * K_) / 256, 256, 0, stream>>>(topidx, bbox, anch, boxes);
  mask_kernel<<<(B_ * 128 * 32) / 4, 256, 0, stream>>>(boxes, mask);
  nms_kernel<<<B_, 64, 0, stream>>>(mask, boxes, out);
}

// Round 3
// 499.032 us; speedup vs baseline: 2.1153x; 1.0147x over previous
//
#include <hip/hip_runtime.h>

#define B_ 4
#define N_ 1000000
#define K_ 2048
#define P_ 1000
#define CAP_ 8192
#define THR_ 0.7f
#define NF4_ 500000  // float4 count per batch of (N,2) float array

// ---- workspace layout (bytes) ----
// hist   : B * 65536 * 4 = 1,048,576
// meta   : 256  (per batch: [0]=threshold bucket, [1]=candidate count)
// cand   : B * CAP * 8   = 262,144   (uint2: key, idx)
// topidx : B * K * 4     = 32,768
// boxes  : B * K * 16    = 131,072
// mask   : B * K * 32 * 8 = 2,097,152
#define OFF_HIST 0
#define OFF_META 1048576
#define OFF_CAND (OFF_META + 256)
#define OFF_TOPI (OFF_CAND + 262144)
#define OFF_BOX  (OFF_TOPI + 32768)
#define OFF_MASK (OFF_BOX + 131072)

__device__ __forceinline__ unsigned fkey(float f) {
  unsigned u = __float_as_uint(f);
  return (u & 0x80000000u) ? ~u : (u | 0x80000000u);
}

__device__ __forceinline__ unsigned long long readlane64(unsigned long long v, int l) {
  unsigned lo = (unsigned)__builtin_amdgcn_readlane((int)(unsigned)(v & 0xffffffffull), l);
  unsigned hi = (unsigned)__builtin_amdgcn_readlane((int)(unsigned)(v >> 32), l);
  return ((unsigned long long)hi << 32) | (unsigned long long)lo;
}

// ---- K1: LDS-privatized histogram of top-16 bits of monotonic key ----
// 65536 buckets as packed u16 pairs: 32768 LDS words = 128 KB.
// 1024 threads/block -> 16 waves/CU despite the 1-block/CU LDS cap.
// 8 float4 preloaded per thread -> 128 B/lane in flight.
// Per-block elements <= 8192*2 + tail < 65536, so no packed-half overflow.
__global__ void __launch_bounds__(1024) hist_kernel(const float4* __restrict__ probs4,
                                                    unsigned* __restrict__ hist) {
  int b = blockIdx.y;
  __shared__ unsigned h[32768];
  for (int i = threadIdx.x; i < 32768; i += 1024) h[i] = 0u;
  __syncthreads();
  const float4* p4 = probs4 + (size_t)b * NF4_;
  int base = blockIdx.x * 8192;
  float4 v[8];
  bool ok[8];
#pragma unroll
  for (int c = 0; c < 8; ++c) {
    int i4 = base + c * 1024 + threadIdx.x;
    ok[c] = (i4 < NF4_);
    if (ok[c]) v[c] = p4[i4];
  }
#pragma unroll
  for (int c = 0; c < 8; ++c) {
    if (ok[c]) {
      unsigned b0 = fkey(v[c].y) >> 16, b1 = fkey(v[c].w) >> 16;
      atomicAdd(&h[b0 >> 1], 1u << ((b0 & 1u) << 4));
      atomicAdd(&h[b1 >> 1], 1u << ((b1 & 1u) << 4));
    }
  }
  __syncthreads();
  // flush nonzero counters to the per-batch global histogram
  unsigned* g = hist + ((size_t)b << 16);
  for (int w = threadIdx.x; w < 32768; w += 1024) {
    unsigned x = h[w];
    if (x) {
      unsigned c0 = x & 0xFFFFu, c1 = x >> 16;
      if (c0) atomicAdd(&g[2 * w], c0);
      if (c1) atomicAdd(&g[2 * w + 1], c1);
    }
  }
}

// ---- K2: find smallest bucket cb with count(bucket >= cb) >= K ----
__global__ void select_kernel(const unsigned* __restrict__ hist, unsigned* __restrict__ meta) {
  int b = blockIdx.x, t = threadIdx.x;  // 256 threads
  __shared__ unsigned suf[256];
  __shared__ int tc_s;
  __shared__ unsigned above_s;
  const unsigned* g = hist + ((size_t)b << 16);
  const uint4* h4 = (const uint4*)g;
  // coarse: thread t sums buckets [t*256, (t+1)*256)
  unsigned sum = 0;
  for (int j = 0; j < 64; ++j) {
    uint4 v = h4[t * 64 + j];
    sum += v.x + v.y + v.z + v.w;
  }
  suf[t] = sum;
  __syncthreads();
  for (int off = 1; off < 256; off <<= 1) {
    unsigned add = (t + off < 256) ? suf[t + off] : 0u;
    __syncthreads();
    suf[t] += add;
    __syncthreads();
  }
  unsigned nxt = (t < 255) ? suf[t + 1] : 0u;
  if (suf[t] >= K_ && (t == 255 || nxt < K_)) { tc_s = t; above_s = nxt; }
  __syncthreads();
  int tc = tc_s;
  unsigned above = above_s;
  // fine: thread t handles bucket tc*256 + t
  unsigned bs = g[tc * 256 + t];
  __syncthreads();
  suf[t] = bs;
  __syncthreads();
  for (int off = 1; off < 256; off <<= 1) {
    unsigned add = (t + off < 256) ? suf[t + off] : 0u;
    __syncthreads();
    suf[t] += add;
    __syncthreads();
  }
  unsigned nxt2 = (t < 255) ? suf[t + 1] : 0u;
  if (above + suf[t] >= K_ && (t == 255 || above + nxt2 < K_))
    meta[b * 4 + 0] = (unsigned)(tc * 256 + t);
}

// ---- K3: compact candidates (bucket >= cb), 16 elems/thread, wave-agg atomics ----
__global__ void __launch_bounds__(256) compact_kernel(const float4* __restrict__ probs4,
                                                      unsigned* __restrict__ meta,
                                                      uint2* __restrict__ cand) {
  int b = blockIdx.y;
  unsigned cb = meta[b * 4 + 0];
  const float4* p4 = probs4 + (size_t)b * NF4_;
  int base = blockIdx.x * 2048;
  int lane = threadIdx.x & 63;
  float4 v[8];
  bool ok[8];
#pragma unroll
  for (int c = 0; c < 8; ++c) {
    int i4 = base + c * 256 + threadIdx.x;
    ok[c] = (i4 < NF4_);
    if (ok[c]) v[c] = p4[i4];
  }
#pragma unroll
  for (int c = 0; c < 8; ++c) {
    int i4 = base + c * 256 + threadIdx.x;
    unsigned k0 = ok[c] ? fkey(v[c].y) : 0u;
    unsigned k1 = ok[c] ? fkey(v[c].w) : 0u;
    bool p0 = ok[c] && ((k0 >> 16) >= cb);
    bool p1 = ok[c] && ((k1 >> 16) >= cb);
#pragma unroll
    for (int s = 0; s < 2; ++s) {
      bool pass = s ? p1 : p0;
      unsigned key = s ? k1 : k0;
      unsigned long long m = __ballot(pass);
      if (m) {
        if (pass) {
          int leader = __ffsll(m) - 1;
          unsigned bpos = 0;
          if (lane == leader) bpos = atomicAdd(&meta[b * 4 + 1], (unsigned)__popcll(m));
          bpos = __shfl(bpos, leader, 64);
          unsigned pos = bpos + (unsigned)__popcll(m & ((1ull << lane) - 1ull));
          if (pos < CAP_) cand[(size_t)b * CAP_ + pos] = make_uint2(key, (unsigned)(2 * i4 + s));
        }
      }
    }
  }
}

// ---- K4: exact rank by counting (stable: key desc, idx asc) ----
__global__ void rank_kernel(const uint2* __restrict__ cand, const unsigned* __restrict__ meta,
                            unsigned* __restrict__ topidx) {
  int b = blockIdx.y;
  unsigned M = meta[b * 4 + 1];
  if (M > CAP_) M = CAP_;
  if ((unsigned)(blockIdx.x * 256) >= M) return;  // uniform per block, before barriers
  __shared__ uint2 tile[1024];
  int ci = blockIdx.x * 256 + threadIdx.x;
  bool act = ci < (int)M;
  uint2 me = make_uint2(0u, 0u);
  if (act) me = cand[(size_t)b * CAP_ + ci];
  unsigned long long my = ((unsigned long long)me.x << 32) | (unsigned long long)(unsigned)(~me.y);
  unsigned rank = 0;
  for (unsigned base = 0; base < M; base += 1024) {
    unsigned n = (M - base < 1024u) ? (M - base) : 1024u;
    for (unsigned t = threadIdx.x; t < n; t += 256) tile[t] = cand[(size_t)b * CAP_ + base + t];
    __syncthreads();
    if (act) {
      unsigned n2 = n >> 1;
      const uint4* t4 = (const uint4*)tile;
      for (unsigned j = 0; j < n2; ++j) {
        uint4 v = t4[j];
        unsigned long long c0 = ((unsigned long long)v.x << 32) | (unsigned long long)(unsigned)(~v.y);
        unsigned long long c1 = ((unsigned long long)v.z << 32) | (unsigned long long)(unsigned)(~v.w);
        rank += (unsigned)(c0 > my) + (unsigned)(c1 > my);
      }
      if (n & 1) {
        uint2 v = tile[n - 1];
        unsigned long long c0 = ((unsigned long long)v.x << 32) | (unsigned long long)(unsigned)(~v.y);
        rank += (unsigned)(c0 > my);
      }
    }
    __syncthreads();
  }
  if (act && rank < K_) topidx[(b << 11) + rank] = me.y;
}

// ---- K5: gather anchors/deltas, decode boxes, clip ----
__global__ void boxes_kernel(const unsigned* __restrict__ topidx, const float4* __restrict__ bbox,
                             const float4* __restrict__ anch, float4* __restrict__ boxes) {
  int g = blockIdx.x * 256 + threadIdx.x;  // B_*K_
  int b = g >> 11;
  unsigned idx = topidx[g];
  size_t base = (size_t)b * N_ + idx;
  float4 a = anch[base];
  float4 d = bbox[base];
  float d0 = d.x * 0.1f, d1 = d.y * 0.1f, d2 = d.z * 0.2f, d3 = d.w * 0.2f;
  float h = a.z - a.x, w = a.w - a.y;
  float cy = (a.x + 0.5f * h) + d0 * h;
  float cx = (a.y + 0.5f * w) + d1 * w;
  float h2 = h * expf(d2);
  float w2 = w * expf(d3);
  float y1 = cy - 0.5f * h2, x1 = cx - 0.5f * w2;
  float y2 = cy + 0.5f * h2, x2 = cx + 0.5f * w2;
  y1 = fminf(fmaxf(y1, 0.f), 1.f);
  x1 = fminf(fmaxf(x1, 0.f), 1.f);
  y2 = fminf(fmaxf(y2, 0.f), 1.f);
  x2 = fminf(fmaxf(x2, 0.f), 1.f);
  boxes[g] = make_float4(y1, x1, y2, x2);
}

// ---- K6: IoU suppression bitmask, one 64-bit word per wave-ballot ----
__global__ void mask_kernel(const float4* __restrict__ boxes, unsigned long long* __restrict__ mask) {
  int wid = blockIdx.x * 4 + (threadIdx.x >> 6);  // 16384 waves total
  int lane = threadIdx.x & 63;
  int b = wid >> 12;         // 4096 waves per batch
  int rb = (wid >> 5) & 127; // row block of 16
  int jb = wid & 31;         // 64-column block
  int j = (jb << 6) + lane;
  float4 bj = boxes[(b << 11) + j];
  float areaJ = (bj.z - bj.x) * (bj.w - bj.y);
#pragma unroll
  for (int r = 0; r < 16; ++r) {
    int i = (rb << 4) + r;
    float4 bi = boxes[(b << 11) + i];
    float areaI = (bi.z - bi.x) * (bi.w - bi.y);
    float yA = fmaxf(bi.x, bj.x), xA = fmaxf(bi.y, bj.y);
    float yB = fminf(bi.z, bj.z), xB = fminf(bi.w, bj.w);
    float ih = fmaxf(yB - yA, 0.f), iw = fmaxf(xB - xA, 0.f);
    float inter = ih * iw;
    float uni = areaI + areaJ - inter;
    float iou = inter / (uni + 1e-8f);
    bool pred = (iou > THR_) && (j > i);
    unsigned long long bits = __ballot(pred);
    if (lane == 0) mask[((size_t)((b << 11) + i) << 5) + jb] = bits;
  }
}

// ---- K7: sequential greedy NMS reduce + output ----
__global__ void nms_kernel(const unsigned long long* __restrict__ mask,
                           const float4* __restrict__ boxes, float4* __restrict__ out) {
  int b = blockIdx.x;
  int lane = threadIdx.x;  // 64 threads = 1 wave
  __shared__ unsigned long long keptm[32];
  __shared__ int pre[32];
  __shared__ int sel[P_];
  if (lane < 32) keptm[lane] = 0ull;
  for (int r = lane; r < P_; r += 64) sel[r] = -1;
  __syncthreads();
  unsigned long long rem = 0ull;  // lane w (<32) owns suppressed-bits word w
  int cnt = 0;
  for (int c = 0; c < 32; ++c) {
    // lane k holds row (c*64+k)'s word c (intra-chunk suppression)
    unsigned long long rin = mask[((size_t)((b << 11) + (c << 6) + lane) << 5) + c];
    unsigned long long cur = readlane64(rem, c);
    unsigned long long kept = 0ull;
#pragma unroll
    for (int k = 0; k < 64; ++k) {
      unsigned long long rk = readlane64(rin, k);
      unsigned long long alive = ((cur >> k) & 1ull) ^ 1ull;
      unsigned long long selm = 0ull - alive;
      cur |= rk & selm;
      kept |= alive << k;
    }
    if (lane == 0) keptm[c] = kept;
    cnt += (int)__popcll(kept);
    // fold kept rows' full masks into rem (lane-parallel over words)
    if (lane < 32) {
      const unsigned long long* rowp = mask + (((size_t)((b << 11) + (c << 6))) << 5) + lane;
#pragma unroll 8
      for (int k = 0; k < 64; ++k) {
        unsigned long long row = rowp[(size_t)k << 5];
        unsigned long long s = 0ull - ((kept >> k) & 1ull);
        rem |= row & s;
      }
    }
    if (cnt >= P_) break;  // later chunks cannot affect the first 1000 kept
  }
  __syncthreads();
  if (lane == 0) {
    int run = 0;
    for (int c = 0; c < 32; ++c) { pre[c] = run; run += (int)__popcll(keptm[c]); }
  }
  __syncthreads();
  for (int i = lane; i < K_; i += 64) {
    int c = i >> 6, k = i & 63;
    unsigned long long km = keptm[c];
    if ((km >> k) & 1ull) {
      int rank = pre[c] + (int)__popcll(km & ((1ull << k) - 1ull));
      if (rank < P_) sel[rank] = i;
    }
  }
  __syncthreads();
  for (int r = lane; r < P_; r += 64) {
    int i = sel[r];
    float4 v = make_float4(0.f, 0.f, 0.f, 0.f);
    if (i >= 0) v = boxes[(b << 11) + i];
    out[b * P_ + r] = v;
  }
}

extern "C" void kernel_launch(void* const* d_in, const int* in_sizes, int n_in,
                              void* d_out, int out_size, void* d_ws, size_t ws_size,
                              hipStream_t stream) {
  const float4* probs4 = (const float4*)d_in[0];     // (B,N,2) viewed as float4
  const float4* bbox   = (const float4*)d_in[1];     // (B,N,4)
  const float4* anch   = (const float4*)d_in[2];     // (B,N,4)
  char* ws = (char*)d_ws;
  unsigned* hist = (unsigned*)(ws + OFF_HIST);
  unsigned* meta = (unsigned*)(ws + OFF_META);
  uint2* cand = (uint2*)(ws + OFF_CAND);
  unsigned* topidx = (unsigned*)(ws + OFF_TOPI);
  float4* boxes = (float4*)(ws + OFF_BOX);
  unsigned long long* mask = (unsigned long long*)(ws + OFF_MASK);
  float4* out = (float4*)d_out;

  hipMemsetAsync(ws, 0, OFF_CAND, stream);  // zero hist + meta (ws is poisoned 0xAA)

  hist_kernel<<<dim3(62, B_), 1024, 0, stream>>>(probs4, hist);       // 62*8192 >= 500k f4
  select_kernel<<<B_, 256, 0, stream>>>(hist, meta);
  compact_kernel<<<dim3(245, B_), 256, 0, stream>>>(probs4, meta, cand);  // 245*2048 >= 500k f4
  rank_kernel<<<dim3(CAP_ / 256, B_), 256, 0, stream>>>(cand, meta, topidx);
  boxes_kernel<<<(B_ * K_) / 256, 256, 0, stream>>>(topidx, bbox, anch, boxes);
  mask_kernel<<<(B_ * 128 * 32) / 4, 256, 0, stream>>>(boxes, mask);
  nms_kernel<<<B_, 64, 0, stream>>>(mask, boxes, out);
}

// Round 4
// 335.065 us; speedup vs baseline: 3.1504x; 1.4894x over previous
//
#include <hip/hip_runtime.h>

#define B_ 4
#define N_ 1000000
#define K_ 2048
#define P_ 1000
#define CAP_ 8192
#define THR_ 0.7f
#define NF4_ 500000     // float4 count per batch of (N,2) float array
#define META_STRIDE 32  // u32 per batch -> 128 B: counters on separate cache lines

// ---- workspace layout (bytes) ----
// hist   : B * 65536 * 4 = 1,048,576
// meta   : 1024  (per batch at b*META_STRIDE: [0]=threshold bucket, [1]=candidate count)
// cand   : B * CAP * 8   = 262,144   (uint2: key, idx)
// topidx : B * K * 4     = 32,768
// boxes  : B * K * 16    = 131,072
// mask   : B * K * 32 * 8 = 2,097,152
#define OFF_HIST 0
#define OFF_META 1048576
#define OFF_CAND (OFF_META + 1024)
#define OFF_TOPI (OFF_CAND + 262144)
#define OFF_BOX  (OFF_TOPI + 32768)
#define OFF_MASK (OFF_BOX + 131072)

__device__ __forceinline__ unsigned fkey(float f) {
  unsigned u = __float_as_uint(f);
  return (u & 0x80000000u) ? ~u : (u | 0x80000000u);
}

__device__ __forceinline__ unsigned long long readlane64(unsigned long long v, int l) {
  unsigned lo = (unsigned)__builtin_amdgcn_readlane((int)(unsigned)(v & 0xffffffffull), l);
  unsigned hi = (unsigned)__builtin_amdgcn_readlane((int)(unsigned)(v >> 32), l);
  return ((unsigned long long)hi << 32) | (unsigned long long)lo;
}

#define PIN16(k) asm volatile("" : "+v"(k[0]), "+v"(k[1]), "+v"(k[2]), "+v"(k[3]), \
                                   "+v"(k[4]), "+v"(k[5]), "+v"(k[6]), "+v"(k[7]), \
                                   "+v"(k[8]), "+v"(k[9]), "+v"(k[10]), "+v"(k[11]), \
                                   "+v"(k[12]), "+v"(k[13]), "+v"(k[14]), "+v"(k[15]))

// ---- K1: LDS-privatized histogram of top-16 bits of monotonic key ----
// 65536 buckets as packed u16 pairs: 32768 LDS words = 128 KB.
// 1024 threads/block; 8 float4 pinned in flight per thread.
// Per-block elements = 16384 < 65536, so no packed-half overflow.
__global__ void __launch_bounds__(1024) hist_kernel(const float4* __restrict__ probs4,
                                                    unsigned* __restrict__ hist) {
  int b = blockIdx.y;
  __shared__ unsigned h[32768];
  for (int i = threadIdx.x; i < 32768; i += 1024) h[i] = 0u;
  __syncthreads();
  const float4* p4 = probs4 + (size_t)b * NF4_;
  int base = blockIdx.x * 8192;
  float4 v[8];
#pragma unroll
  for (int c = 0; c < 8; ++c) {
    int i4 = base + c * 1024 + threadIdx.x;
    v[c] = (i4 < NF4_) ? p4[i4] : make_float4(0.f, 0.f, 0.f, 0.f);
  }
  unsigned k[16];
#pragma unroll
  for (int c = 0; c < 8; ++c) { k[2 * c] = fkey(v[c].y) >> 16; k[2 * c + 1] = fkey(v[c].w) >> 16; }
  PIN16(k);
#pragma unroll
  for (int c = 0; c < 8; ++c) {
    int i4 = base + c * 1024 + threadIdx.x;
    if (i4 < NF4_) {
      unsigned b0 = k[2 * c], b1 = k[2 * c + 1];
      atomicAdd(&h[b0 >> 1], 1u << ((b0 & 1u) << 4));
      atomicAdd(&h[b1 >> 1], 1u << ((b1 & 1u) << 4));
    }
  }
  __syncthreads();
  // flush nonzero counters to the per-batch global histogram
  unsigned* g = hist + ((size_t)b << 16);
  for (int w = threadIdx.x; w < 32768; w += 1024) {
    unsigned x = h[w];
    if (x) {
      unsigned c0 = x & 0xFFFFu, c1 = x >> 16;
      if (c0) atomicAdd(&g[2 * w], c0);
      if (c1) atomicAdd(&g[2 * w + 1], c1);
    }
  }
}

// ---- K2: find smallest bucket cb with count(bucket >= cb) >= K ----
__global__ void select_kernel(const unsigned* __restrict__ hist, unsigned* __restrict__ meta) {
  int b = blockIdx.x, t = threadIdx.x;  // 256 threads
  __shared__ unsigned suf[256];
  __shared__ int tc_s;
  __shared__ unsigned above_s;
  const unsigned* g = hist + ((size_t)b << 16);
  const uint4* h4 = (const uint4*)g;
  // coarse: thread t sums buckets [t*256, (t+1)*256)
  unsigned sum = 0;
  for (int j = 0; j < 64; ++j) {
    uint4 v = h4[t * 64 + j];
    sum += v.x + v.y + v.z + v.w;
  }
  suf[t] = sum;
  __syncthreads();
  for (int off = 1; off < 256; off <<= 1) {
    unsigned add = (t + off < 256) ? suf[t + off] : 0u;
    __syncthreads();
    suf[t] += add;
    __syncthreads();
  }
  unsigned nxt = (t < 255) ? suf[t + 1] : 0u;
  if (suf[t] >= K_ && (t == 255 || nxt < K_)) { tc_s = t; above_s = nxt; }
  __syncthreads();
  int tc = tc_s;
  unsigned above = above_s;
  // fine: thread t handles bucket tc*256 + t
  unsigned bs = g[tc * 256 + t];
  __syncthreads();
  suf[t] = bs;
  __syncthreads();
  for (int off = 1; off < 256; off <<= 1) {
    unsigned add = (t + off < 256) ? suf[t + off] : 0u;
    __syncthreads();
    suf[t] += add;
    __syncthreads();
  }
  unsigned nxt2 = (t < 255) ? suf[t + 1] : 0u;
  if (above + suf[t] >= K_ && (t == 255 || above + nxt2 < K_))
    meta[b * META_STRIDE + 0] = (unsigned)(tc * 256 + t);
}

// ---- K3: compact candidates (bucket >= cb) ----
// Two-phase: LDS buffer with block-local counter (cheap LDS atomics), then ONE
// global atomicAdd per block, then cooperative copy-out. Kills the same-line
// device-atomic ping-pong that pinned rounds 1-3 at ~160 us.
__global__ void __launch_bounds__(256) compact_kernel(const float4* __restrict__ probs4,
                                                      unsigned* __restrict__ meta,
                                                      uint2* __restrict__ cand) {
  int b = blockIdx.y;
  __shared__ unsigned lcnt, gbase_s;
  __shared__ uint2 buf[4096];
  if (threadIdx.x == 0) lcnt = 0u;
  __syncthreads();
  unsigned cb = meta[b * META_STRIDE + 0];
  const float4* p4 = probs4 + (size_t)b * NF4_;
  int base = blockIdx.x * 2048;
  int lane = threadIdx.x & 63;
  float4 v[8];
#pragma unroll
  for (int c = 0; c < 8; ++c) {
    int i4 = base + c * 256 + threadIdx.x;
    v[c] = (i4 < NF4_) ? p4[i4] : make_float4(0.f, 0.f, 0.f, 0.f);
  }
  unsigned k[16];
#pragma unroll
  for (int c = 0; c < 8; ++c) { k[2 * c] = fkey(v[c].y); k[2 * c + 1] = fkey(v[c].w); }
  PIN16(k);
#pragma unroll
  for (int c = 0; c < 8; ++c) {
#pragma unroll
    for (int s = 0; s < 2; ++s) {
      int i4 = base + c * 256 + threadIdx.x;
      unsigned key = k[2 * c + s];
      bool pass = (i4 < NF4_) && ((key >> 16) >= cb);
      unsigned long long m = __ballot(pass);
      if (m) {
        int leader = __ffsll(m) - 1;
        unsigned wbase = 0;
        if (lane == leader) wbase = atomicAdd(&lcnt, (unsigned)__popcll(m));
        wbase = __shfl(wbase, leader, 64);
        if (pass) {
          unsigned pos = wbase + (unsigned)__popcll(m & ((1ull << lane) - 1ull));
          buf[pos] = make_uint2(key, (unsigned)(2 * i4 + s));
        }
      }
    }
  }
  __syncthreads();
  unsigned cnt = lcnt;
  if (threadIdx.x == 0) gbase_s = atomicAdd(&meta[b * META_STRIDE + 1], cnt);
  __syncthreads();
  unsigned gbase = gbase_s;
  for (unsigned i = threadIdx.x; i < cnt; i += 256) {
    unsigned pos = gbase + i;
    if (pos < CAP_) cand[(size_t)b * CAP_ + pos] = buf[i];
  }
}

// ---- K4: exact rank by counting (stable: key desc, idx asc) ----
__global__ void rank_kernel(const uint2* __restrict__ cand, const unsigned* __restrict__ meta,
                            unsigned* __restrict__ topidx) {
  int b = blockIdx.y;
  unsigned M = meta[b * META_STRIDE + 1];
  if (M > CAP_) M = CAP_;
  if ((unsigned)(blockIdx.x * 256) >= M) return;  // uniform per block, before barriers
  __shared__ uint2 tile[1024];
  int ci = blockIdx.x * 256 + threadIdx.x;
  bool act = ci < (int)M;
  uint2 me = make_uint2(0u, 0u);
  if (act) me = cand[(size_t)b * CAP_ + ci];
  unsigned long long my = ((unsigned long long)me.x << 32) | (unsigned long long)(unsigned)(~me.y);
  unsigned rank = 0;
  for (unsigned base = 0; base < M; base += 1024) {
    unsigned n = (M - base < 1024u) ? (M - base) : 1024u;
    for (unsigned t = threadIdx.x; t < n; t += 256) tile[t] = cand[(size_t)b * CAP_ + base + t];
    __syncthreads();
    if (act) {
      unsigned n2 = n >> 1;
      const uint4* t4 = (const uint4*)tile;
      for (unsigned j = 0; j < n2; ++j) {
        uint4 v = t4[j];
        unsigned long long c0 = ((unsigned long long)v.x << 32) | (unsigned long long)(unsigned)(~v.y);
        unsigned long long c1 = ((unsigned long long)v.z << 32) | (unsigned long long)(unsigned)(~v.w);
        rank += (unsigned)(c0 > my) + (unsigned)(c1 > my);
      }
      if (n & 1) {
        uint2 v = tile[n - 1];
        unsigned long long c0 = ((unsigned long long)v.x << 32) | (unsigned long long)(unsigned)(~v.y);
        rank += (unsigned)(c0 > my);
      }
    }
    __syncthreads();
  }
  if (act && rank < K_) topidx[(b << 11) + rank] = me.y;
}

// ---- K5: gather anchors/deltas, decode boxes, clip ----
__global__ void boxes_kernel(const unsigned* __restrict__ topidx, const float4* __restrict__ bbox,
                             const float4* __restrict__ anch, float4* __restrict__ boxes) {
  int g = blockIdx.x * 256 + threadIdx.x;  // B_*K_
  int b = g >> 11;
  unsigned idx = topidx[g];
  size_t base = (size_t)b * N_ + idx;
  float4 a = anch[base];
  float4 d = bbox[base];
  float d0 = d.x * 0.1f, d1 = d.y * 0.1f, d2 = d.z * 0.2f, d3 = d.w * 0.2f;
  float h = a.z - a.x, w = a.w - a.y;
  float cy = (a.x + 0.5f * h) + d0 * h;
  float cx = (a.y + 0.5f * w) + d1 * w;
  float h2 = h * expf(d2);
  float w2 = w * expf(d3);
  float y1 = cy - 0.5f * h2, x1 = cx - 0.5f * w2;
  float y2 = cy + 0.5f * h2, x2 = cx + 0.5f * w2;
  y1 = fminf(fmaxf(y1, 0.f), 1.f);
  x1 = fminf(fmaxf(x1, 0.f), 1.f);
  y2 = fminf(fmaxf(y2, 0.f), 1.f);
  x2 = fminf(fmaxf(x2, 0.f), 1.f);
  boxes[g] = make_float4(y1, x1, y2, x2);
}

// ---- K6: IoU suppression bitmask, one 64-bit word per wave-ballot ----
__global__ void mask_kernel(const float4* __restrict__ boxes, unsigned long long* __restrict__ mask) {
  int wid = blockIdx.x * 4 + (threadIdx.x >> 6);  // 16384 waves total
  int lane = threadIdx.x & 63;
  int b = wid >> 12;         // 4096 waves per batch
  int rb = (wid >> 5) & 127; // row block of 16
  int jb = wid & 31;         // 64-column block
  int j = (jb << 6) + lane;
  float4 bj = boxes[(b << 11) + j];
  float areaJ = (bj.z - bj.x) * (bj.w - bj.y);
#pragma unroll
  for (int r = 0; r < 16; ++r) {
    int i = (rb << 4) + r;
    float4 bi = boxes[(b << 11) + i];
    float areaI = (bi.z - bi.x) * (bi.w - bi.y);
    float yA = fmaxf(bi.x, bj.x), xA = fmaxf(bi.y, bj.y);
    float yB = fminf(bi.z, bj.z), xB = fminf(bi.w, bj.w);
    float ih = fmaxf(yB - yA, 0.f), iw = fmaxf(xB - xA, 0.f);
    float inter = ih * iw;
    float uni = areaI + areaJ - inter;
    float iou = inter / (uni + 1e-8f);
    bool pred = (iou > THR_) && (j > i);
    unsigned long long bits = __ballot(pred);
    if (lane == 0) mask[((size_t)((b << 11) + i) << 5) + jb] = bits;
  }
}

// ---- K7: sequential greedy NMS reduce + output ----
// 256 threads: all 4 waves cooperatively stage each 64-row chunk (16 KB) of the
// suppression matrix into LDS (coalesced); wave 0 runs the serial scan + fold
// entirely from LDS (round-3 version did 64 strided global loads/lane/chunk).
__global__ void __launch_bounds__(256) nms_kernel(const unsigned long long* __restrict__ mask,
                                                  const float4* __restrict__ boxes,
                                                  float4* __restrict__ out) {
  int b = blockIdx.x;
  int tid = threadIdx.x;
  int lane = tid & 63, wave = tid >> 6;
  __shared__ unsigned long long rows[64][32];
  __shared__ unsigned long long keptm[32];
  __shared__ int pre[32];
  __shared__ short sel[P_];
  __shared__ int done_s, cnt_s;
  if (tid == 0) { done_s = 0; cnt_s = 0; }
  if (tid < 32) keptm[tid] = 0ull;
  for (int r = tid; r < P_; r += 256) sel[r] = -1;
  __syncthreads();
  unsigned long long rem = 0ull;  // wave0 lane w (<32) owns suppressed-bits word w
  for (int c = 0; c < 32; ++c) {
    const unsigned long long* src = mask + (((size_t)((b << 11) + (c << 6))) << 5);
    for (int i = tid; i < 2048; i += 256) rows[i >> 5][i & 31] = src[i];
    __syncthreads();
    if (wave == 0) {
      unsigned long long rin = rows[lane][c];  // row (c*64+lane)'s word c
      unsigned long long cur = readlane64(rem, c);
      unsigned long long kept = 0ull;
#pragma unroll
      for (int k2 = 0; k2 < 64; ++k2) {
        unsigned long long rk = readlane64(rin, k2);
        unsigned long long alive = ((cur >> k2) & 1ull) ^ 1ull;
        cur |= rk & (0ull - alive);
        kept |= alive << k2;
      }
      if (lane == 0) {
        keptm[c] = kept;
        cnt_s += (int)__popcll(kept);
        if (cnt_s >= P_) done_s = 1;  // later chunks cannot affect first 1000 kept
      }
      if (lane < 32) {
#pragma unroll 8
        for (int k2 = 0; k2 < 64; ++k2)
          rem |= rows[k2][lane] & (0ull - ((kept >> k2) & 1ull));
      }
    }
    __syncthreads();
    if (done_s) break;
  }
  if (tid == 0) {
    int run = 0;
    for (int c = 0; c < 32; ++c) { pre[c] = run; run += (int)__popcll(keptm[c]); }
  }
  __syncthreads();
  for (int i = tid; i < K_; i += 256) {
    int c = i >> 6, k2 = i & 63;
    unsigned long long km = keptm[c];
    if ((km >> k2) & 1ull) {
      int rank = pre[c] + (int)__popcll(km & ((1ull << k2) - 1ull));
      if (rank < P_) sel[rank] = (short)i;
    }
  }
  __syncthreads();
  for (int r = tid; r < P_; r += 256) {
    int i = sel[r];
    float4 v = make_float4(0.f, 0.f, 0.f, 0.f);
    if (i >= 0) v = boxes[(b << 11) + i];
    out[b * P_ + r] = v;
  }
}

extern "C" void kernel_launch(void* const* d_in, const int* in_sizes, int n_in,
                              void* d_out, int out_size, void* d_ws, size_t ws_size,
                              hipStream_t stream) {
  const float4* probs4 = (const float4*)d_in[0];     // (B,N,2) viewed as float4
  const float4* bbox   = (const float4*)d_in[1];     // (B,N,4)
  const float4* anch   = (const float4*)d_in[2];     // (B,N,4)
  char* ws = (char*)d_ws;
  unsigned* hist = (unsigned*)(ws + OFF_HIST);
  unsigned* meta = (unsigned*)(ws + OFF_META);
  uint2* cand = (uint2*)(ws + OFF_CAND);
  unsigned* topidx = (unsigned*)(ws + OFF_TOPI);
  float4* boxes = (float4*)(ws + OFF_BOX);
  unsigned long long* mask = (unsigned long long*)(ws + OFF_MASK);
  float4* out = (float4*)d_out;

  hipMemsetAsync(ws, 0, OFF_CAND, stream);  // zero hist + meta (ws is poisoned 0xAA)

  hist_kernel<<<dim3(62, B_), 1024, 0, stream>>>(probs4, hist);           // 62*8192 >= 500k f4
  select_kernel<<<B_, 256, 0, stream>>>(hist, meta);
  compact_kernel<<<dim3(245, B_), 256, 0, stream>>>(probs4, meta, cand);  // 245*2048 >= 500k f4
  rank_kernel<<<dim3(CAP_ / 256, B_), 256, 0, stream>>>(cand, meta, topidx);
  boxes_kernel<<<(B_ * K_) / 256, 256, 0, stream>>>(topidx, bbox, anch, boxes);
  mask_kernel<<<(B_ * 128 * 32) / 4, 256, 0, stream>>>(boxes, mask);
  nms_kernel<<<B_, 256, 0, stream>>>(mask, boxes, out);
}

// Round 5
// 307.914 us; speedup vs baseline: 3.4282x; 1.0882x over previous
//
#include <hip/hip_runtime.h>

#define B_ 4
#define N_ 1000000
#define K_ 2048
#define P_ 1000
#define CAP_ 8192
#define THR_ 0.7f
#define NF4_ 500000     // float4 count per batch of (N,2) float array
#define META_STRIDE 32  // u32 per batch -> 128 B: counters on separate cache lines

// ---- workspace layout (bytes) ----
// hist   : B * 65536 * 4 = 1,048,576
// meta   : 1024  (per batch at b*META_STRIDE: [0]=threshold bucket, [1]=candidate count)
// coarse : B * 256 * 4 = 4,096
// cand   : B * CAP * 8   = 262,144   (uint2: key, idx)
// topidx : B * K * 4     = 32,768
// boxes  : B * K * 16    = 131,072
// mask   : B * K * 32 * 8 = 2,097,152
#define OFF_HIST 0
#define OFF_META 1048576
#define OFF_COARSE (OFF_META + 1024)
#define OFF_CAND (OFF_COARSE + 4096)
#define OFF_TOPI (OFF_CAND + 262144)
#define OFF_BOX  (OFF_TOPI + 32768)
#define OFF_MASK (OFF_BOX + 131072)

__device__ __forceinline__ unsigned fkey(float f) {
  unsigned u = __float_as_uint(f);
  return (u & 0x80000000u) ? ~u : (u | 0x80000000u);
}

__device__ __forceinline__ unsigned long long readlane64(unsigned long long v, int l) {
  unsigned lo = (unsigned)__builtin_amdgcn_readlane((int)(unsigned)(v & 0xffffffffull), l);
  unsigned hi = (unsigned)__builtin_amdgcn_readlane((int)(unsigned)(v >> 32), l);
  return ((unsigned long long)hi << 32) | (unsigned long long)lo;
}

#define PIN16(k) asm volatile("" : "+v"(k[0]), "+v"(k[1]), "+v"(k[2]), "+v"(k[3]), \
                                   "+v"(k[4]), "+v"(k[5]), "+v"(k[6]), "+v"(k[7]), \
                                   "+v"(k[8]), "+v"(k[9]), "+v"(k[10]), "+v"(k[11]), \
                                   "+v"(k[12]), "+v"(k[13]), "+v"(k[14]), "+v"(k[15]))

// ---- K1: LDS-privatized histogram of top-16 bits of monotonic key ----
__global__ void __launch_bounds__(1024) hist_kernel(const float4* __restrict__ probs4,
                                                    unsigned* __restrict__ hist) {
  int b = blockIdx.y;
  __shared__ unsigned h[32768];
  for (int i = threadIdx.x; i < 32768; i += 1024) h[i] = 0u;
  __syncthreads();
  const float4* p4 = probs4 + (size_t)b * NF4_;
  int base = blockIdx.x * 8192;
  float4 v[8];
#pragma unroll
  for (int c = 0; c < 8; ++c) {
    int i4 = base + c * 1024 + threadIdx.x;
    v[c] = (i4 < NF4_) ? p4[i4] : make_float4(0.f, 0.f, 0.f, 0.f);
  }
  unsigned k[16];
#pragma unroll
  for (int c = 0; c < 8; ++c) { k[2 * c] = fkey(v[c].y) >> 16; k[2 * c + 1] = fkey(v[c].w) >> 16; }
  PIN16(k);
#pragma unroll
  for (int c = 0; c < 8; ++c) {
    int i4 = base + c * 1024 + threadIdx.x;
    if (i4 < NF4_) {
      unsigned b0 = k[2 * c], b1 = k[2 * c + 1];
      atomicAdd(&h[b0 >> 1], 1u << ((b0 & 1u) << 4));
      atomicAdd(&h[b1 >> 1], 1u << ((b1 & 1u) << 4));
    }
  }
  __syncthreads();
  unsigned* g = hist + ((size_t)b << 16);
  for (int w = threadIdx.x; w < 32768; w += 1024) {
    unsigned x = h[w];
    if (x) {
      unsigned c0 = x & 0xFFFFu, c1 = x >> 16;
      if (c0) atomicAdd(&g[2 * w], c0);
      if (c1) atomicAdd(&g[2 * w + 1], c1);
    }
  }
}

// ---- K2a: coarse sums — one wave per 256-bucket group, coalesced + shfl-reduce ----
__global__ void __launch_bounds__(64) coarse_kernel(const unsigned* __restrict__ hist,
                                                    unsigned* __restrict__ coarse) {
  int b = blockIdx.y, g = blockIdx.x, lane = threadIdx.x;
  const uint4* h4 = (const uint4*)(hist + (((size_t)b) << 16) + ((size_t)g << 8));
  uint4 v = h4[lane];
  unsigned s = v.x + v.y + v.z + v.w;
#pragma unroll
  for (int off = 32; off >= 1; off >>= 1) s += __shfl_xor(s, off, 64);
  if (lane == 0) coarse[b * 256 + g] = s;
}

// ---- K2b: find smallest bucket cb with count(bucket >= cb) >= K ----
__global__ void select_kernel(const unsigned* __restrict__ hist, const unsigned* __restrict__ coarse,
                              unsigned* __restrict__ meta) {
  int b = blockIdx.x, t = threadIdx.x;  // 256 threads
  __shared__ unsigned suf[256];
  __shared__ int tc_s;
  __shared__ unsigned above_s;
  const unsigned* g = hist + ((size_t)b << 16);
  suf[t] = coarse[b * 256 + t];
  __syncthreads();
  for (int off = 1; off < 256; off <<= 1) {
    unsigned add = (t + off < 256) ? suf[t + off] : 0u;
    __syncthreads();
    suf[t] += add;
    __syncthreads();
  }
  unsigned nxt = (t < 255) ? suf[t + 1] : 0u;
  if (suf[t] >= K_ && (t == 255 || nxt < K_)) { tc_s = t; above_s = nxt; }
  __syncthreads();
  int tc = tc_s;
  unsigned above = above_s;
  unsigned bs = g[tc * 256 + t];
  __syncthreads();
  suf[t] = bs;
  __syncthreads();
  for (int off = 1; off < 256; off <<= 1) {
    unsigned add = (t + off < 256) ? suf[t + off] : 0u;
    __syncthreads();
    suf[t] += add;
    __syncthreads();
  }
  unsigned nxt2 = (t < 255) ? suf[t + 1] : 0u;
  if (above + suf[t] >= K_ && (t == 255 || above + nxt2 < K_))
    meta[b * META_STRIDE + 0] = (unsigned)(tc * 256 + t);
}

// ---- K3: compact candidates (bucket >= cb), LDS-buffered, 1 global atomic/block ----
__global__ void __launch_bounds__(256) compact_kernel(const float4* __restrict__ probs4,
                                                      unsigned* __restrict__ meta,
                                                      uint2* __restrict__ cand) {
  int b = blockIdx.y;
  __shared__ unsigned lcnt, gbase_s;
  __shared__ uint2 buf[4096];
  if (threadIdx.x == 0) lcnt = 0u;
  __syncthreads();
  unsigned cb = meta[b * META_STRIDE + 0];
  const float4* p4 = probs4 + (size_t)b * NF4_;
  int base = blockIdx.x * 2048;
  int lane = threadIdx.x & 63;
  float4 v[8];
#pragma unroll
  for (int c = 0; c < 8; ++c) {
    int i4 = base + c * 256 + threadIdx.x;
    v[c] = (i4 < NF4_) ? p4[i4] : make_float4(0.f, 0.f, 0.f, 0.f);
  }
  unsigned k[16];
#pragma unroll
  for (int c = 0; c < 8; ++c) { k[2 * c] = fkey(v[c].y); k[2 * c + 1] = fkey(v[c].w); }
  PIN16(k);
#pragma unroll
  for (int c = 0; c < 8; ++c) {
#pragma unroll
    for (int s = 0; s < 2; ++s) {
      int i4 = base + c * 256 + threadIdx.x;
      unsigned key = k[2 * c + s];
      bool pass = (i4 < NF4_) && ((key >> 16) >= cb);
      unsigned long long m = __ballot(pass);
      if (m) {
        int leader = __ffsll(m) - 1;
        unsigned wbase = 0;
        if (lane == leader) wbase = atomicAdd(&lcnt, (unsigned)__popcll(m));
        wbase = __shfl(wbase, leader, 64);
        if (pass) {
          unsigned pos = wbase + (unsigned)__popcll(m & ((1ull << lane) - 1ull));
          buf[pos] = make_uint2(key, (unsigned)(2 * i4 + s));
        }
      }
    }
  }
  __syncthreads();
  unsigned cnt = lcnt;
  if (threadIdx.x == 0) gbase_s = atomicAdd(&meta[b * META_STRIDE + 1], cnt);
  __syncthreads();
  unsigned gbase = gbase_s;
  for (unsigned i = threadIdx.x; i < cnt; i += 256) {
    unsigned pos = gbase + i;
    if (pos < CAP_) cand[(size_t)b * CAP_ + pos] = buf[i];
  }
}

// ---- K4: exact rank by counting (stable: key desc, idx asc) ----
__global__ void rank_kernel(const uint2* __restrict__ cand, const unsigned* __restrict__ meta,
                            unsigned* __restrict__ topidx) {
  int b = blockIdx.y;
  unsigned M = meta[b * META_STRIDE + 1];
  if (M > CAP_) M = CAP_;
  if ((unsigned)(blockIdx.x * 256) >= M) return;
  __shared__ uint2 tile[1024];
  int ci = blockIdx.x * 256 + threadIdx.x;
  bool act = ci < (int)M;
  uint2 me = make_uint2(0u, 0u);
  if (act) me = cand[(size_t)b * CAP_ + ci];
  unsigned long long my = ((unsigned long long)me.x << 32) | (unsigned long long)(unsigned)(~me.y);
  unsigned rank = 0;
  for (unsigned base = 0; base < M; base += 1024) {
    unsigned n = (M - base < 1024u) ? (M - base) : 1024u;
    for (unsigned t = threadIdx.x; t < n; t += 256) tile[t] = cand[(size_t)b * CAP_ + base + t];
    __syncthreads();
    if (act) {
      unsigned n2 = n >> 1;
      const uint4* t4 = (const uint4*)tile;
      for (unsigned j = 0; j < n2; ++j) {
        uint4 v = t4[j];
        unsigned long long c0 = ((unsigned long long)v.x << 32) | (unsigned long long)(unsigned)(~v.y);
        unsigned long long c1 = ((unsigned long long)v.z << 32) | (unsigned long long)(unsigned)(~v.w);
        rank += (unsigned)(c0 > my) + (unsigned)(c1 > my);
      }
      if (n & 1) {
        uint2 v = tile[n - 1];
        unsigned long long c0 = ((unsigned long long)v.x << 32) | (unsigned long long)(unsigned)(~v.y);
        rank += (unsigned)(c0 > my);
      }
    }
    __syncthreads();
  }
  if (act && rank < K_) topidx[(b << 11) + rank] = me.y;
}

// ---- K5: gather anchors/deltas, decode boxes, clip ----
__global__ void boxes_kernel(const unsigned* __restrict__ topidx, const float4* __restrict__ bbox,
                             const float4* __restrict__ anch, float4* __restrict__ boxes) {
  int g = blockIdx.x * 256 + threadIdx.x;  // B_*K_
  int b = g >> 11;
  unsigned idx = topidx[g];
  size_t base = (size_t)b * N_ + idx;
  float4 a = anch[base];
  float4 d = bbox[base];
  float d0 = d.x * 0.1f, d1 = d.y * 0.1f, d2 = d.z * 0.2f, d3 = d.w * 0.2f;
  float h = a.z - a.x, w = a.w - a.y;
  float cy = (a.x + 0.5f * h) + d0 * h;
  float cx = (a.y + 0.5f * w) + d1 * w;
  float h2 = h * expf(d2);
  float w2 = w * expf(d3);
  float y1 = cy - 0.5f * h2, x1 = cx - 0.5f * w2;
  float y2 = cy + 0.5f * h2, x2 = cx + 0.5f * w2;
  y1 = fminf(fmaxf(y1, 0.f), 1.f);
  x1 = fminf(fmaxf(x1, 0.f), 1.f);
  y2 = fminf(fmaxf(y2, 0.f), 1.f);
  x2 = fminf(fmaxf(x2, 0.f), 1.f);
  boxes[g] = make_float4(y1, x1, y2, x2);
}

// ---- K6: IoU suppression bitmask (upper-triangular word-blocks only) ----
__global__ void mask_kernel(const float4* __restrict__ boxes, unsigned long long* __restrict__ mask) {
  int wid = blockIdx.x * 4 + (threadIdx.x >> 6);  // 16384 waves total
  int lane = threadIdx.x & 63;
  int b = wid >> 12;         // 4096 waves per batch
  int rb = (wid >> 5) & 127; // row block of 16
  int jb = wid & 31;         // 64-column block
  if (jb < (rb >> 2)) return;  // word-blocks below the row's chunk are never read
  int j = (jb << 6) + lane;
  float4 bj = boxes[(b << 11) + j];
  float areaJ = (bj.z - bj.x) * (bj.w - bj.y);
#pragma unroll
  for (int r = 0; r < 16; ++r) {
    int i = (rb << 4) + r;
    float4 bi = boxes[(b << 11) + i];
    float areaI = (bi.z - bi.x) * (bi.w - bi.y);
    float yA = fmaxf(bi.x, bj.x), xA = fmaxf(bi.y, bj.y);
    float yB = fminf(bi.z, bj.z), xB = fminf(bi.w, bj.w);
    float ih = fmaxf(yB - yA, 0.f), iw = fmaxf(xB - xA, 0.f);
    float inter = ih * iw;
    float uni = areaI + areaJ - inter;
    float iou = inter / (uni + 1e-8f);
    bool pred = (iou > THR_) && (j > i);
    unsigned long long bits = __ballot(pred);
    if (lane == 0) mask[((size_t)((b << 11) + i) << 5) + jb] = bits;
  }
}

// ---- K7: greedy NMS, single wave, barrier-light ----
// Register-prefetch next 16 KB chunk (coalesced dwordx2) while scanning/folding
// the current one from LDS. Scan is uniform (SGPR chain); fold is lane-parallel
// (2 lanes per word x 32 rows, shfl_xor combine, rem in registers) and
// triangular (words > c only; earlier words are dead).
__global__ void __launch_bounds__(64) nms_kernel(const unsigned long long* __restrict__ mask,
                                                 const float4* __restrict__ boxes,
                                                 float4* __restrict__ out) {
  int b = blockIdx.x;
  int lane = threadIdx.x;  // 64 threads = 1 wave
  __shared__ unsigned long long rows[64][33];  // pad 33: scan column read = 4-way not 64-way
  __shared__ unsigned long long keptm[32];
  __shared__ int pre[32];
  __shared__ short sel[P_];
  if (lane < 32) keptm[lane] = 0ull;
  for (int r = lane; r < P_; r += 64) sel[r] = -1;
  int w = lane & 31, half = lane >> 5;
  const unsigned long long* mbase = mask + (((size_t)(b << 11)) << 5);
  unsigned long long r0[32];
  // stage chunk 0 (all words)
#pragma unroll
  for (int j = 0; j < 32; ++j) r0[j] = mbase[j * 64 + lane];
#pragma unroll
  for (int j = 0; j < 32; ++j) rows[2 * j + half][w] = r0[j];
  __syncthreads();
  unsigned long long rem = 0ull;  // lane owns word w (two copies, halves in sync)
  int cnt = 0;
  for (int c = 0; c < 32; ++c) {
    // prefetch chunk c+1, words > c only (triangular)
    bool pf = (c < 31) && (w > c);
    if (pf) {
      const unsigned long long* srcN = mbase + (((size_t)(c + 1)) << 11);
#pragma unroll
      for (int j = 0; j < 32; ++j) r0[j] = srcN[j * 64 + lane];
    }
    // --- scan chunk c (uniform serial, 64 steps) ---
    unsigned long long rin = rows[lane][c];          // row (64c+lane), word c
    unsigned long long cur = readlane64(rem, c);     // suppressed bits for this chunk
    unsigned long long kept = 0ull;
#pragma unroll
    for (int k2 = 0; k2 < 64; ++k2) {
      unsigned long long rk = readlane64(rin, k2);
      unsigned long long alive = ((cur >> k2) & 1ull) ^ 1ull;
      cur |= rk & (0ull - alive);
      kept |= alive << k2;
    }
    if (lane == 0) keptm[c] = kept;
    cnt += (int)__popcll(kept);
    if (cnt >= P_) break;  // later chunks cannot affect first 1000 kept
    // --- fold kept rows into rem (lane-parallel, words > c only) ---
    if (w > c) {
      unsigned long long acc = 0ull;
#pragma unroll
      for (int k2 = 0; k2 < 32; ++k2) {
        int row = half * 32 + k2;
        acc |= rows[row][w] & (0ull - ((kept >> row) & 1ull));
      }
      acc |= __shfl_xor(acc, 32, 64);
      rem |= acc;
    }
    // --- commit prefetched chunk c+1 to LDS ---
    if (pf) {
#pragma unroll
      for (int j = 0; j < 32; ++j) rows[2 * j + half][w] = r0[j];
    }
    __syncthreads();
  }
  __syncthreads();
  if (lane == 0) {
    int run = 0;
    for (int c = 0; c < 32; ++c) { pre[c] = run; run += (int)__popcll(keptm[c]); }
  }
  __syncthreads();
  for (int i = lane; i < K_; i += 64) {
    int c = i >> 6, k2 = i & 63;
    unsigned long long km = keptm[c];
    if ((km >> k2) & 1ull) {
      int rank = pre[c] + (int)__popcll(km & ((1ull << k2) - 1ull));
      if (rank < P_) sel[rank] = (short)i;
    }
  }
  __syncthreads();
  for (int r = lane; r < P_; r += 64) {
    int i = sel[r];
    float4 v = make_float4(0.f, 0.f, 0.f, 0.f);
    if (i >= 0) v = boxes[(b << 11) + i];
    out[b * P_ + r] = v;
  }
}

extern "C" void kernel_launch(void* const* d_in, const int* in_sizes, int n_in,
                              void* d_out, int out_size, void* d_ws, size_t ws_size,
                              hipStream_t stream) {
  const float4* probs4 = (const float4*)d_in[0];     // (B,N,2) viewed as float4
  const float4* bbox   = (const float4*)d_in[1];     // (B,N,4)
  const float4* anch   = (const float4*)d_in[2];     // (B,N,4)
  char* ws = (char*)d_ws;
  unsigned* hist = (unsigned*)(ws + OFF_HIST);
  unsigned* meta = (unsigned*)(ws + OFF_META);
  unsigned* coarse = (unsigned*)(ws + OFF_COARSE);
  uint2* cand = (uint2*)(ws + OFF_CAND);
  unsigned* topidx = (unsigned*)(ws + OFF_TOPI);
  float4* boxes = (float4*)(ws + OFF_BOX);
  unsigned long long* mask = (unsigned long long*)(ws + OFF_MASK);
  float4* out = (float4*)d_out;

  hipMemsetAsync(ws, 0, OFF_COARSE, stream);  // zero hist + meta

  hist_kernel<<<dim3(62, B_), 1024, 0, stream>>>(probs4, hist);           // 62*8192 >= 500k f4
  coarse_kernel<<<dim3(256, B_), 64, 0, stream>>>(hist, coarse);
  select_kernel<<<B_, 256, 0, stream>>>(hist, coarse, meta);
  compact_kernel<<<dim3(245, B_), 256, 0, stream>>>(probs4, meta, cand);  // 245*2048 >= 500k f4
  rank_kernel<<<dim3(CAP_ / 256, B_), 256, 0, stream>>>(cand, meta, topidx);
  boxes_kernel<<<(B_ * K_) / 256, 256, 0, stream>>>(topidx, bbox, anch, boxes);
  mask_kernel<<<(B_ * 128 * 32) / 4, 256, 0, stream>>>(boxes, mask);
  nms_kernel<<<B_, 64, 0, stream>>>(mask, boxes, out);
}